// Round 2
// baseline (509.985 us; speedup 1.0000x reference)
//
#include <hip/hip_runtime.h>
#include <math.h>

#define NROW 16384   // B*N rows
#define NCOL 4096
#define CDIM 256
#define DKDIM 64
#define SCALE 0.125f // DK^-0.5

typedef float v4f __attribute__((ext_vector_type(4)));
typedef __attribute__((ext_vector_type(8))) short short8v;  // 8 bf16 = 4 VGPR
typedef __attribute__((ext_vector_type(4))) float f32x4;

// ---- monotone float<->u32 key helpers (unsigned compare == float compare) ----
__device__ __forceinline__ unsigned mono(float v) {
  unsigned u = __float_as_uint(v);
  unsigned s = (unsigned)(((int)u) >> 31);
  return u ^ (s | 0x80000000u);
}
__device__ __forceinline__ float unmono(unsigned k) {
  unsigned u = (k & 0x80000000u) ? (k ^ 0x80000000u) : ~k;
  return __uint_as_float(u);
}
__device__ __forceinline__ unsigned short f2bf(float f) {  // RNE bf16
  unsigned u = __float_as_uint(f);
  u += 0x7FFFu + ((u >> 16) & 1u);
  return (unsigned short)(u >> 16);
}
__device__ __forceinline__ unsigned umaxu(unsigned a, unsigned b) { return a > b ? a : b; }

// ---- top-8 maintenance on packed keys (proven group-of-8 insert logic) ----
__device__ __forceinline__ void ins8(unsigned tk[8], unsigned& tmin, int& tmpos, unsigned v) {
  #pragma unroll
  for (int j = 0; j < 8; ++j) if (j == tmpos) tk[j] = v;
  tmin = tk[0]; tmpos = 0;
  #pragma unroll
  for (int j = 1; j < 8; ++j) if (tk[j] < tmin) { tmin = tk[j]; tmpos = j; }
}
__device__ __forceinline__ unsigned umax8(const unsigned kv[8]) {
  unsigned a = umaxu(umaxu(kv[0], kv[1]), umaxu(kv[2], kv[3]));
  unsigned b = umaxu(umaxu(kv[4], kv[5]), umaxu(kv[6], kv[7]));
  return umaxu(a, b);
}
// register-array variants (no LDS)
__device__ __forceinline__ void seed8r(const unsigned kv[8],
                                       unsigned tk[8], unsigned& tmin, int& tmpos) {
  #pragma unroll
  for (int j = 0; j < 8; ++j) tk[j] = kv[j];
  tmin = tk[0]; tmpos = 0;
  #pragma unroll
  for (int j = 1; j < 8; ++j) if (tk[j] < tmin) { tmin = tk[j]; tmpos = j; }
}
__device__ __forceinline__ void scan8r(const unsigned kvin[8],
                                       unsigned tk[8], unsigned& tmin, int& tmpos) {
  unsigned kv[8];
  #pragma unroll
  for (int j = 0; j < 8; ++j) kv[j] = kvin[j];
  unsigned gm = umax8(kv);
  #pragma unroll
  for (int pass = 0; pass < 2; ++pass) {
    if (__any(gm > tmin)) {            // wave-uniform branch
      if (gm > tmin) {                 // per-lane insert (keys unique: col in low bits)
        ins8(tk, tmin, tmpos, gm);
        #pragma unroll
        for (int j = 0; j < 8; ++j) if (kv[j] == gm) kv[j] = 0u;
      }
      gm = umax8(kv);
    }
  }
  if (__any(gm > tmin)) {              // rare: >=3 qualifiers in this group
    #pragma unroll
    for (int j = 0; j < 8; ++j) if (kv[j] > tmin) ins8(tk, tmin, tmpos, kv[j]);
  }
}
// LDS-pointer variants (merge phase)
__device__ __forceinline__ void seed8(const unsigned* __restrict__ sp,
                                      unsigned tk[8], unsigned& tmin, int& tmpos) {
  uint4 ka = *(const uint4*)(sp);
  uint4 kb = *(const uint4*)(sp + 4);
  unsigned kv[8] = {ka.x, ka.y, ka.z, ka.w, kb.x, kb.y, kb.z, kb.w};
  seed8r(kv, tk, tmin, tmpos);
}
__device__ __forceinline__ void scan8(const unsigned* __restrict__ sp,
                                      unsigned tk[8], unsigned& tmin, int& tmpos) {
  uint4 ka = *(const uint4*)(sp);
  uint4 kb = *(const uint4*)(sp + 4);
  unsigned kv[8] = {ka.x, ka.y, ka.z, ka.w, kb.x, kb.y, kb.z, kb.w};
  scan8r(kv, tk, tmin, tmpos);
}

// ---------------- Kernel 1: fused Q/K projection + out zero-fill ----------
// The zero-fill of the 268 MB output lives HERE: qk_proj's compute path after
// x-staging uses only s_load (W) and ds_read (x) -- both lgkmcnt -- so the
// interleaved nontemporal stores (vmcnt) never block anything and drain fully
// under the FMA loop. s_cand then never waits behind stores.
__global__ __launch_bounds__(512, 2) void qk_proj(
    const float* __restrict__ x, const float* __restrict__ Wq,
    const float* __restrict__ Wk, float* __restrict__ Qt,
    float* __restrict__ Kt, unsigned short* __restrict__ Qh,
    unsigned short* __restrict__ Kh, float* __restrict__ out) {
  __shared__ float4 xs4[64][65];  // row stride 65 f4-units -> bank-group spread
  const int t = threadIdx.x;
  const int rb = blockIdx.x;      // 256 blocks of 64 rows
  {
    const float4* xg = (const float4*)(x + (size_t)rb * 64 * CDIM);
    #pragma unroll
    for (int i = 0; i < 8; ++i) {
      int idx = i * 512 + t;      // 0..4095
      xs4[idx >> 6][idx & 63] = xg[idx];
    }
  }
  __syncthreads();

  const int lane = t & 63;
  const int wu = __builtin_amdgcn_readfirstlane(t >> 6);  // wave id, uniform
  const int proj = wu >> 2;
  const int chunk = wu & 3;       // d-chunk: d = chunk*16 .. +15
  const float* __restrict__ Wp = proj ? Wk : Wq;

  // my block's 64x4096 output region: 65536 float4
  v4f* __restrict__ ofill = (v4f*)out + (size_t)rb * 65536;
  const v4f z = {0.f, 0.f, 0.f, 0.f};

  float acc[16];
  #pragma unroll
  for (int j = 0; j < 16; ++j) acc[j] = 0.f;

  #pragma unroll 4
  for (int cs = 0; cs < 64; ++cs) {        // 4 c's per step
    {  // 2 fire-and-forget zero stores per step: 64*2*512 = 65536 total
      int g0 = cs * 1024 + t;
      __builtin_nontemporal_store(z, &ofill[g0]);
      __builtin_nontemporal_store(z, &ofill[g0 + 512]);
    }
    float4 xv = xs4[lane][cs];
    const float xc[4] = {xv.x, xv.y, xv.z, xv.w};
    #pragma unroll
    for (int i = 0; i < 4; ++i) {
      const float4* __restrict__ w4 =
          (const float4*)(Wp + (size_t)(cs * 4 + i) * DKDIM + chunk * 16);
      float4 wa = w4[0], wb = w4[1], wc = w4[2], wd = w4[3];
      float xi = xc[i];
      acc[0]  = fmaf(xi, wa.x, acc[0]);  acc[1]  = fmaf(xi, wa.y, acc[1]);
      acc[2]  = fmaf(xi, wa.z, acc[2]);  acc[3]  = fmaf(xi, wa.w, acc[3]);
      acc[4]  = fmaf(xi, wb.x, acc[4]);  acc[5]  = fmaf(xi, wb.y, acc[5]);
      acc[6]  = fmaf(xi, wb.z, acc[6]);  acc[7]  = fmaf(xi, wb.w, acc[7]);
      acc[8]  = fmaf(xi, wc.x, acc[8]);  acc[9]  = fmaf(xi, wc.y, acc[9]);
      acc[10] = fmaf(xi, wc.z, acc[10]); acc[11] = fmaf(xi, wc.w, acc[11]);
      acc[12] = fmaf(xi, wd.x, acc[12]); acc[13] = fmaf(xi, wd.y, acc[13]);
      acc[14] = fmaf(xi, wd.z, acc[14]); acc[15] = fmaf(xi, wd.w, acc[15]);
    }
  }

  const int gr = rb * 64 + lane;  // global row
  // fp32 row-major [row][64] (exact-recompute source in finalize)
  float* Of = (proj ? Kt : Qt) + (size_t)gr * 64 + chunk * 16;
  #pragma unroll
  for (int i = 0; i < 4; ++i) {
    float4 o = {acc[4 * i], acc[4 * i + 1], acc[4 * i + 2], acc[4 * i + 3]};
    ((float4*)Of)[i] = o;
  }
  // bf16 row-major [row][64] (MFMA operand source in s_cand)
  unsigned short* Oh = (proj ? Kh : Qh) + (size_t)gr * 64 + chunk * 16;
  unsigned hp[8];
  #pragma unroll
  for (int i = 0; i < 8; ++i)
    hp[i] = (unsigned)f2bf(acc[2 * i]) | ((unsigned)f2bf(acc[2 * i + 1]) << 16);
  uint4 h0 = {hp[0], hp[1], hp[2], hp[3]};
  uint4 h1 = {hp[4], hp[5], hp[6], hp[7]};
  ((uint4*)Oh)[0] = h0;
  ((uint4*)Oh)[1] = h1;
}

// ---------------- Kernel 2: MFMA S-tiles + per-row approx top-8 per chunk ----
// Pure compute now (no out traffic). Each wave: 16 rows x 512 cols.
// Per 16x16 tile: 2x mfma_f32_16x16x32_bf16; accumulators pack to
// (monotone-value | col) u32 keys held in REGISTERS. Scan: 4 groups of 8
// tiles; per group each lane runs the group-of-8 early-out scan on its 4
// row-streams (row = lk*4+i, cols {16*ct + l15}). One LDS merge at the end
// (16 lanes x top-8 -> 128 keys/row -> top-8). No __syncthreads.
__global__ __launch_bounds__(256, 4) void s_cand(
    const unsigned short* __restrict__ Qh, const unsigned short* __restrict__ Kh,
    unsigned* __restrict__ wsk) {
  __shared__ unsigned keys[4][16 * 132];  // 33792 B -> 4 blocks/CU
  const int t = threadIdx.x;
  const int lane = t & 63;
  const int w = __builtin_amdgcn_readfirstlane(t >> 6);
  const int f = blockIdx.x;        // 0..2047, XCD swizzle decode
  const int xs = f & 7;
  const int i5 = f >> 3;
  const int combo = xs * 4 + (i5 >> 6);   // 0..31
  const int rbL = i5 & 63;
  const int b = combo >> 3;        // batch
  const int chunk = combo & 7;     // col-chunk of 512

  const int l15 = lane & 15, lk = lane >> 4;
  // A-fragments: my 16 Q rows. row = lane&15, k = (lane>>4)*8+j (+32 for a1).
  const int rowg = (b << 12) + rbL * 64 + w * 16 + l15;
  const short8v a0 = *(const short8v*)(Qh + (size_t)rowg * 64 + lk * 8);
  const short8v a1 = *(const short8v*)(Qh + (size_t)rowg * 64 + lk * 8 + 32);

  const unsigned short* Kb = Kh + ((size_t)(b << 12)) * 64;

  unsigned tk[4][8]; unsigned tmin[4]; int tmpos[4];

  #pragma unroll 1
  for (int g = 0; g < 4; ++g) {    // 4 groups of 8 col-tiles
    unsigned kv[4][8];
    #pragma unroll
    for (int t8 = 0; t8 < 8; ++t8) {
      const int ct = g * 8 + t8;
      const int col = chunk * 512 + ct * 16 + l15;
      const unsigned short* kp = Kb + (size_t)col * 64 + lk * 8;
      const short8v b0 = *(const short8v*)(kp);        // B: col=lane&15, k-half 0
      const short8v b1 = *(const short8v*)(kp + 32);   // k-half 1
      f32x4 acc = {0.f, 0.f, 0.f, 0.f};
      acc = __builtin_amdgcn_mfma_f32_16x16x32_bf16(a0, b0, acc, 0, 0, 0);
      acc = __builtin_amdgcn_mfma_f32_16x16x32_bf16(a1, b1, acc, 0, 0, 0);
      // C/D: col=lane&15, row=(lane>>4)*4+i (m89-verified). Pack to keys.
      #pragma unroll
      for (int i = 0; i < 4; ++i)
        kv[i][t8] = (mono(acc[i]) & 0xFFFFF000u) | (unsigned)col;
    }
    if (g == 0) {
      #pragma unroll
      for (int i = 0; i < 4; ++i) seed8r(kv[i], tk[i], tmin[i], tmpos[i]);
    } else {
      #pragma unroll
      for (int i = 0; i < 4; ++i) scan8r(kv[i], tk[i], tmin[i], tmpos[i]);
    }
  }

  // ---- merge: per row, 16 lanes x top-8 -> 128 keys -> top-8 ----
  unsigned* krow = keys[w];
  #pragma unroll
  for (int i = 0; i < 4; ++i) {    // write my 4 row-streams' top-8
    uint4 s0 = {tk[i][0], tk[i][1], tk[i][2], tk[i][3]};
    uint4 s1 = {tk[i][4], tk[i][5], tk[i][6], tk[i][7]};
    uint4* mp4 = (uint4*)(krow + (lk * 4 + i) * 132 + l15 * 8);
    mp4[0] = s0; mp4[1] = s1;
  }
  // same-wave DS ops are in-order: reads below see all writes above
  const int myrow = lane >> 2, q = lane & 3;   // 4 lanes per row scan 32 keys
  unsigned mt[8]; unsigned mmin; int mmpos;
  {
    const unsigned* sp = krow + myrow * 132 + q * 32;
    seed8(sp, mt, mmin, mmpos);
    scan8(sp + 8, mt, mmin, mmpos);
    scan8(sp + 16, mt, mmin, mmpos);
    scan8(sp + 24, mt, mmin, mmpos);
  }
  {  // 4 -> 1 per-row reduction (reuse LDS low region; prior reads done)
    uint4 s0 = {mt[0], mt[1], mt[2], mt[3]};
    uint4 s1 = {mt[4], mt[5], mt[6], mt[7]};
    uint4* mp4 = (uint4*)(krow + myrow * 36 + q * 8);
    mp4[0] = s0; mp4[1] = s1;
  }
  if (lane < 16) {
    const unsigned* mp = krow + lane * 36;
    unsigned ft[8]; unsigned fmin; int fmpos;
    seed8(mp, ft, fmin, fmpos);
    scan8(mp + 8, ft, fmin, fmpos);
    scan8(mp + 16, ft, fmin, fmpos);
    scan8(mp + 24, ft, fmin, fmpos);
    const int grow = (b << 12) + rbL * 64 + w * 16 + lane;
    uint4 o0 = {ft[0], ft[1], ft[2], ft[3]};
    uint4 o1 = {ft[4], ft[5], ft[6], ft[7]};
    uint4* wp = (uint4*)(wsk + (size_t)grow * 64 + chunk * 8);
    wp[0] = o0; wp[1] = o1;
  }
}

// ---------------- Kernel 3: exact recompute of 64 candidates + softmax ------
// 1 wave per row; lane = candidate. Exact fp32 dot in the SAME sequential fma
// order as the original kernel, then 8x shuffle-max extraction on full-
// precision monotone keys, identical __expf softmax, scatter.
__global__ __launch_bounds__(256) void finalize(
    const float* __restrict__ Qt, const float* __restrict__ Kt,
    const unsigned* __restrict__ wsk, float* __restrict__ out) {
  const int t = threadIdx.x;
  const int lane = t & 63;
  const int w = t >> 6;
  const int row = blockIdx.x * 4 + w;
  const int b = row >> 12;
  const unsigned key = wsk[(size_t)row * 64 + lane];
  const int col = (int)(key & 0xFFFu);   // batch-local column
  const float4* Kp = (const float4*)(Kt + ((size_t)((b << 12) + col)) * 64);
  const float4* Qp = (const float4*)(Qt + (size_t)row * 64);  // uniform -> s_load
  float s = 0.f;
  #pragma unroll
  for (int g = 0; g < 16; ++g) {
    float4 qf = Qp[g];
    float4 kf = Kp[g];
    s = fmaf(qf.x, kf.x, s);
    s = fmaf(qf.y, kf.y, s);
    s = fmaf(qf.z, kf.z, s);
    s = fmaf(qf.w, kf.w, s);
  }
  unsigned kx = mono(s);  // full precision: exact ordering
  float vals[8]; int cols[8];
  #pragma unroll
  for (int it = 0; it < 8; ++it) {
    unsigned m = kx;
    #pragma unroll
    for (int d = 1; d < 64; d <<= 1) m = umaxu(m, (unsigned)__shfl_xor((int)m, d, 64));
    unsigned long long win = __ballot(kx == m);
    int wl = (int)__ffsll(win) - 1;
    cols[it] = __shfl(col, wl, 64);
    vals[it] = unmono(m);
    if (lane == wl) kx = 0u;   // exclude winner
  }
  float e[8], sum = 0.f;
  #pragma unroll
  for (int it = 0; it < 8; ++it) { e[it] = __expf((vals[it] - vals[0]) * SCALE); sum += e[it]; }
  float inv = 1.f / sum;
  if (lane == 0) {
    float* orow = out + ((size_t)row << 12);
    #pragma unroll
    for (int it = 0; it < 8; ++it) orow[cols[it]] = e[it] * inv;
  }
}

extern "C" void kernel_launch(void* const* d_in, const int* in_sizes, int n_in,
                              void* d_out, int out_size, void* d_ws, size_t ws_size,
                              hipStream_t stream) {
  const float* x  = (const float*)d_in[0];
  const float* Wq = (const float*)d_in[1];
  const float* Wk = (const float*)d_in[2];
  float* out = (float*)d_out;

  char* ws = (char*)d_ws;                       // 16 MB total
  float* Qt = (float*)ws;                       // 4 MB fp32 [row][64]
  float* Kt = (float*)(ws + ((size_t)4 << 20)); // 4 MB
  unsigned short* Qh = (unsigned short*)(ws + ((size_t)8 << 20));   // 2 MB bf16
  unsigned short* Kh = (unsigned short*)(ws + ((size_t)10 << 20));  // 2 MB
  unsigned* wsk = (unsigned*)(ws + ((size_t)12 << 20));             // 4 MB keys

  qk_proj<<<dim3(NROW / 64), 512, 0, stream>>>(x, Wq, Wk, Qt, Kt, Qh, Kh, out);
  s_cand<<<2048, 256, 0, stream>>>(Qh, Kh, wsk);
  finalize<<<NROW / 4, 256, 0, stream>>>(Qt, Kt, wsk, out);
}

// Round 3
// 469.172 us; speedup vs baseline: 1.0870x; 1.0870x over previous
//
#include <hip/hip_runtime.h>
#include <math.h>

#define NROW 16384   // B*N rows
#define NCOL 4096
#define CDIM 256
#define DKDIM 64
#define SCALE 0.125f // DK^-0.5

typedef float v4f __attribute__((ext_vector_type(4)));
typedef __attribute__((ext_vector_type(8))) short short8v;  // 8 bf16 = 4 VGPR
typedef __attribute__((ext_vector_type(4))) float f32x4;

// ---- monotone float<->u32 key helpers (unsigned compare == float compare) ----
__device__ __forceinline__ unsigned mono(float v) {
  unsigned u = __float_as_uint(v);
  unsigned s = (unsigned)(((int)u) >> 31);
  return u ^ (s | 0x80000000u);
}
__device__ __forceinline__ float unmono(unsigned k) {
  unsigned u = (k & 0x80000000u) ? (k ^ 0x80000000u) : ~k;
  return __uint_as_float(u);
}
__device__ __forceinline__ unsigned short f2bf(float f) {  // RNE bf16
  unsigned u = __float_as_uint(f);
  u += 0x7FFFu + ((u >> 16) & 1u);
  return (unsigned short)(u >> 16);
}
__device__ __forceinline__ unsigned umaxu(unsigned a, unsigned b) { return a > b ? a : b; }

// ---- top-8 maintenance on packed keys (proven group-of-8 insert logic) ----
__device__ __forceinline__ void ins8(unsigned tk[8], unsigned& tmin, int& tmpos, unsigned v) {
  #pragma unroll
  for (int j = 0; j < 8; ++j) if (j == tmpos) tk[j] = v;
  tmin = tk[0]; tmpos = 0;
  #pragma unroll
  for (int j = 1; j < 8; ++j) if (tk[j] < tmin) { tmin = tk[j]; tmpos = j; }
}
__device__ __forceinline__ unsigned umax8(const unsigned kv[8]) {
  unsigned a = umaxu(umaxu(kv[0], kv[1]), umaxu(kv[2], kv[3]));
  unsigned b = umaxu(umaxu(kv[4], kv[5]), umaxu(kv[6], kv[7]));
  return umaxu(a, b);
}
// register-array variants (no LDS)
__device__ __forceinline__ void seed8r(const unsigned kv[8],
                                       unsigned tk[8], unsigned& tmin, int& tmpos) {
  #pragma unroll
  for (int j = 0; j < 8; ++j) tk[j] = kv[j];
  tmin = tk[0]; tmpos = 0;
  #pragma unroll
  for (int j = 1; j < 8; ++j) if (tk[j] < tmin) { tmin = tk[j]; tmpos = j; }
}
__device__ __forceinline__ void scan8r(const unsigned kvin[8],
                                       unsigned tk[8], unsigned& tmin, int& tmpos) {
  unsigned kv[8];
  #pragma unroll
  for (int j = 0; j < 8; ++j) kv[j] = kvin[j];
  unsigned gm = umax8(kv);
  #pragma unroll
  for (int pass = 0; pass < 2; ++pass) {
    if (__any(gm > tmin)) {            // wave-uniform branch
      if (gm > tmin) {                 // per-lane insert (keys unique: col in low bits)
        ins8(tk, tmin, tmpos, gm);
        #pragma unroll
        for (int j = 0; j < 8; ++j) if (kv[j] == gm) kv[j] = 0u;
      }
      gm = umax8(kv);
    }
  }
  if (__any(gm > tmin)) {              // rare: >=3 qualifiers in this group
    #pragma unroll
    for (int j = 0; j < 8; ++j) if (kv[j] > tmin) ins8(tk, tmin, tmpos, kv[j]);
  }
}
// LDS-pointer variants (merge phase)
__device__ __forceinline__ void seed8(const unsigned* __restrict__ sp,
                                      unsigned tk[8], unsigned& tmin, int& tmpos) {
  uint4 ka = *(const uint4*)(sp);
  uint4 kb = *(const uint4*)(sp + 4);
  unsigned kv[8] = {ka.x, ka.y, ka.z, ka.w, kb.x, kb.y, kb.z, kb.w};
  seed8r(kv, tk, tmin, tmpos);
}
__device__ __forceinline__ void scan8(const unsigned* __restrict__ sp,
                                      unsigned tk[8], unsigned& tmin, int& tmpos) {
  uint4 ka = *(const uint4*)(sp);
  uint4 kb = *(const uint4*)(sp + 4);
  unsigned kv[8] = {ka.x, ka.y, ka.z, ka.w, kb.x, kb.y, kb.z, kb.w};
  scan8r(kv, tk, tmin, tmpos);
}

// ---------------- Kernel 1: fused Q/K projection (fp32 + bf16 row-major) ----
// Round-1 form: no output fill here (round-2 showed interleaved NT stores in
// this kernel cost +42 us net -- the fill now lives in finalize).
__global__ __launch_bounds__(512, 2) void qk_proj(
    const float* __restrict__ x, const float* __restrict__ Wq,
    const float* __restrict__ Wk, float* __restrict__ Qt,
    float* __restrict__ Kt, unsigned short* __restrict__ Qh,
    unsigned short* __restrict__ Kh) {
  __shared__ float4 xs4[64][65];  // row stride 65 f4-units -> bank-group spread
  const int t = threadIdx.x;
  const int rb = blockIdx.x;      // 256 blocks of 64 rows
  {
    const float4* xg = (const float4*)(x + (size_t)rb * 64 * CDIM);
    #pragma unroll
    for (int i = 0; i < 8; ++i) {
      int idx = i * 512 + t;      // 0..4095
      xs4[idx >> 6][idx & 63] = xg[idx];
    }
  }
  __syncthreads();

  const int lane = t & 63;
  const int wu = __builtin_amdgcn_readfirstlane(t >> 6);  // wave id, uniform
  const int proj = wu >> 2;
  const int chunk = wu & 3;       // d-chunk: d = chunk*16 .. +15
  const float* __restrict__ Wp = proj ? Wk : Wq;

  float acc[16];
  #pragma unroll
  for (int j = 0; j < 16; ++j) acc[j] = 0.f;

  #pragma unroll 4
  for (int cs = 0; cs < 64; ++cs) {        // 4 c's per step
    float4 xv = xs4[lane][cs];
    const float xc[4] = {xv.x, xv.y, xv.z, xv.w};
    #pragma unroll
    for (int i = 0; i < 4; ++i) {
      const float4* __restrict__ w4 =
          (const float4*)(Wp + (size_t)(cs * 4 + i) * DKDIM + chunk * 16);
      float4 wa = w4[0], wb = w4[1], wc = w4[2], wd = w4[3];
      float xi = xc[i];
      acc[0]  = fmaf(xi, wa.x, acc[0]);  acc[1]  = fmaf(xi, wa.y, acc[1]);
      acc[2]  = fmaf(xi, wa.z, acc[2]);  acc[3]  = fmaf(xi, wa.w, acc[3]);
      acc[4]  = fmaf(xi, wb.x, acc[4]);  acc[5]  = fmaf(xi, wb.y, acc[5]);
      acc[6]  = fmaf(xi, wb.z, acc[6]);  acc[7]  = fmaf(xi, wb.w, acc[7]);
      acc[8]  = fmaf(xi, wc.x, acc[8]);  acc[9]  = fmaf(xi, wc.y, acc[9]);
      acc[10] = fmaf(xi, wc.z, acc[10]); acc[11] = fmaf(xi, wc.w, acc[11]);
      acc[12] = fmaf(xi, wd.x, acc[12]); acc[13] = fmaf(xi, wd.y, acc[13]);
      acc[14] = fmaf(xi, wd.z, acc[14]); acc[15] = fmaf(xi, wd.w, acc[15]);
    }
  }

  const int gr = rb * 64 + lane;  // global row
  // fp32 row-major [row][64] (exact-recompute source in finalize)
  float* Of = (proj ? Kt : Qt) + (size_t)gr * 64 + chunk * 16;
  #pragma unroll
  for (int i = 0; i < 4; ++i) {
    float4 o = {acc[4 * i], acc[4 * i + 1], acc[4 * i + 2], acc[4 * i + 3]};
    ((float4*)Of)[i] = o;
  }
  // bf16 row-major [row][64] (MFMA operand source in s_cand)
  unsigned short* Oh = (proj ? Kh : Qh) + (size_t)gr * 64 + chunk * 16;
  unsigned hp[8];
  #pragma unroll
  for (int i = 0; i < 8; ++i)
    hp[i] = (unsigned)f2bf(acc[2 * i]) | ((unsigned)f2bf(acc[2 * i + 1]) << 16);
  uint4 h0 = {hp[0], hp[1], hp[2], hp[3]};
  uint4 h1 = {hp[4], hp[5], hp[6], hp[7]};
  ((uint4*)Oh)[0] = h0;
  ((uint4*)Oh)[1] = h1;
}

// ---------------- Kernel 2: MFMA S-tiles + per-row approx top-8 per chunk ----
// Pure compute (no out traffic). Each wave: 16 rows x 512 cols.
// Per 16x16 tile: 2x mfma_f32_16x16x32_bf16; accumulators pack to
// (monotone-value | col) u32 keys held in REGISTERS. Scan: 4 groups of 8
// tiles; one LDS merge at the end. No __syncthreads (wave-private LDS).
__global__ __launch_bounds__(256, 4) void s_cand(
    const unsigned short* __restrict__ Qh, const unsigned short* __restrict__ Kh,
    unsigned* __restrict__ wsk) {
  __shared__ unsigned keys[4][16 * 132];  // 33792 B -> 4 blocks/CU
  const int t = threadIdx.x;
  const int lane = t & 63;
  const int w = __builtin_amdgcn_readfirstlane(t >> 6);
  const int f = blockIdx.x;        // 0..2047, XCD swizzle decode
  const int xs = f & 7;
  const int i5 = f >> 3;
  const int combo = xs * 4 + (i5 >> 6);   // 0..31
  const int rbL = i5 & 63;
  const int b = combo >> 3;        // batch
  const int chunk = combo & 7;     // col-chunk of 512

  const int l15 = lane & 15, lk = lane >> 4;
  // A-fragments: my 16 Q rows. row = lane&15, k = (lane>>4)*8+j (+32 for a1).
  const int rowg = (b << 12) + rbL * 64 + w * 16 + l15;
  const short8v a0 = *(const short8v*)(Qh + (size_t)rowg * 64 + lk * 8);
  const short8v a1 = *(const short8v*)(Qh + (size_t)rowg * 64 + lk * 8 + 32);

  const unsigned short* Kb = Kh + ((size_t)(b << 12)) * 64;

  unsigned tk[4][8]; unsigned tmin[4]; int tmpos[4];

  #pragma unroll 1
  for (int g = 0; g < 4; ++g) {    // 4 groups of 8 col-tiles
    unsigned kv[4][8];
    #pragma unroll
    for (int t8 = 0; t8 < 8; ++t8) {
      const int ct = g * 8 + t8;
      const int col = chunk * 512 + ct * 16 + l15;
      const unsigned short* kp = Kb + (size_t)col * 64 + lk * 8;
      const short8v b0 = *(const short8v*)(kp);        // B: col=lane&15, k-half 0
      const short8v b1 = *(const short8v*)(kp + 32);   // k-half 1
      f32x4 acc = {0.f, 0.f, 0.f, 0.f};
      acc = __builtin_amdgcn_mfma_f32_16x16x32_bf16(a0, b0, acc, 0, 0, 0);
      acc = __builtin_amdgcn_mfma_f32_16x16x32_bf16(a1, b1, acc, 0, 0, 0);
      // C/D: col=lane&15, row=(lane>>4)*4+i (m89-verified). Pack to keys.
      #pragma unroll
      for (int i = 0; i < 4; ++i)
        kv[i][t8] = (mono(acc[i]) & 0xFFFFF000u) | (unsigned)col;
    }
    if (g == 0) {
      #pragma unroll
      for (int i = 0; i < 4; ++i) seed8r(kv[i], tk[i], tmin[i], tmpos[i]);
    } else {
      #pragma unroll
      for (int i = 0; i < 4; ++i) scan8r(kv[i], tk[i], tmin[i], tmpos[i]);
    }
  }

  // ---- merge: per row, 16 lanes x top-8 -> 128 keys -> top-8 ----
  unsigned* krow = keys[w];
  #pragma unroll
  for (int i = 0; i < 4; ++i) {    // write my 4 row-streams' top-8
    uint4 s0 = {tk[i][0], tk[i][1], tk[i][2], tk[i][3]};
    uint4 s1 = {tk[i][4], tk[i][5], tk[i][6], tk[i][7]};
    uint4* mp4 = (uint4*)(krow + (lk * 4 + i) * 132 + l15 * 8);
    mp4[0] = s0; mp4[1] = s1;
  }
  // same-wave DS ops are in-order: reads below see all writes above
  const int myrow = lane >> 2, q = lane & 3;   // 4 lanes per row scan 32 keys
  unsigned mt[8]; unsigned mmin; int mmpos;
  {
    const unsigned* sp = krow + myrow * 132 + q * 32;
    seed8(sp, mt, mmin, mmpos);
    scan8(sp + 8, mt, mmin, mmpos);
    scan8(sp + 16, mt, mmin, mmpos);
    scan8(sp + 24, mt, mmin, mmpos);
  }
  {  // 4 -> 1 per-row reduction (reuse LDS low region; prior reads done)
    uint4 s0 = {mt[0], mt[1], mt[2], mt[3]};
    uint4 s1 = {mt[4], mt[5], mt[6], mt[7]};
    uint4* mp4 = (uint4*)(krow + myrow * 36 + q * 8);
    mp4[0] = s0; mp4[1] = s1;
  }
  if (lane < 16) {
    const unsigned* mp = krow + lane * 36;
    unsigned ft[8]; unsigned fmin; int fmpos;
    seed8(mp, ft, fmin, fmpos);
    scan8(mp + 8, ft, fmin, fmpos);
    scan8(mp + 16, ft, fmin, fmpos);
    scan8(mp + 24, ft, fmin, fmpos);
    const int grow = (b << 12) + rbL * 64 + w * 16 + lane;
    uint4 o0 = {ft[0], ft[1], ft[2], ft[3]};
    uint4 o1 = {ft[4], ft[5], ft[6], ft[7]};
    uint4* wp = (uint4*)(wsk + (size_t)grow * 64 + chunk * 8);
    wp[0] = o0; wp[1] = o1;
  }
}

// ---------------- Kernel 3: exact recompute + softmax + fused fill/scatter --
// 1 wave per row; lane = candidate. All memory ops are loads-before-stores:
// read wsk/Q/K -> exact fp32 dots (same fma order as original) -> shuffle-max
// extraction -> softmax -> ONE coalesced NT-store pass that writes the whole
// 16 KB row with the 8 values patched in via compare-select (zero-fill and
// scatter fused: no second pass, no store-ordering hazard, fill runs at
// pure write BW like fillBufferAligned).
__global__ __launch_bounds__(256) void finalize(
    const float* __restrict__ Qt, const float* __restrict__ Kt,
    const unsigned* __restrict__ wsk, float* __restrict__ out) {
  const int t = threadIdx.x;
  const int lane = t & 63;
  const int w = t >> 6;
  const int row = blockIdx.x * 4 + w;
  const int b = row >> 12;
  const unsigned key = wsk[(size_t)row * 64 + lane];
  const int col = (int)(key & 0xFFFu);   // batch-local column
  const float4* Kp = (const float4*)(Kt + ((size_t)((b << 12) + col)) * 64);
  const float4* Qp = (const float4*)(Qt + (size_t)row * 64);  // uniform -> s_load
  float s = 0.f;
  #pragma unroll
  for (int g = 0; g < 16; ++g) {
    float4 qf = Qp[g];
    float4 kf = Kp[g];
    s = fmaf(qf.x, kf.x, s);
    s = fmaf(qf.y, kf.y, s);
    s = fmaf(qf.z, kf.z, s);
    s = fmaf(qf.w, kf.w, s);
  }
  unsigned kx = mono(s);  // full precision: exact ordering
  float vals[8]; int cols[8];
  #pragma unroll
  for (int it = 0; it < 8; ++it) {
    unsigned m = kx;
    #pragma unroll
    for (int d = 1; d < 64; d <<= 1) m = umaxu(m, (unsigned)__shfl_xor((int)m, d, 64));
    unsigned long long win = __ballot(kx == m);
    int wl = (int)__ffsll(win) - 1;
    cols[it] = __shfl(col, wl, 64);
    vals[it] = unmono(m);
    if (lane == wl) kx = 0u;   // exclude winner
  }
  float vq[8]; float sum = 0.f;
  #pragma unroll
  for (int it = 0; it < 8; ++it) { vq[it] = __expf((vals[it] - vals[0]) * SCALE); sum += vq[it]; }
  float inv = 1.f / sum;
  #pragma unroll
  for (int it = 0; it < 8; ++it) vq[it] *= inv;

  // fused zero-fill + scatter (coalesced: lane-consecutive float4 per step)
  v4f* orow4 = (v4f*)(out + ((size_t)row << 12));
  #pragma unroll
  for (int i = 0; i < 16; ++i) {
    const int base = i * 256 + lane * 4;
    v4f z = {0.f, 0.f, 0.f, 0.f};
    #pragma unroll
    for (int q = 0; q < 8; ++q) {
      z.x = (cols[q] == base)     ? vq[q] : z.x;
      z.y = (cols[q] == base + 1) ? vq[q] : z.y;
      z.z = (cols[q] == base + 2) ? vq[q] : z.z;
      z.w = (cols[q] == base + 3) ? vq[q] : z.w;
    }
    __builtin_nontemporal_store(z, &orow4[(size_t)i * 64 + lane]);
  }
}

extern "C" void kernel_launch(void* const* d_in, const int* in_sizes, int n_in,
                              void* d_out, int out_size, void* d_ws, size_t ws_size,
                              hipStream_t stream) {
  const float* x  = (const float*)d_in[0];
  const float* Wq = (const float*)d_in[1];
  const float* Wk = (const float*)d_in[2];
  float* out = (float*)d_out;

  char* ws = (char*)d_ws;                       // 16 MB total
  float* Qt = (float*)ws;                       // 4 MB fp32 [row][64]
  float* Kt = (float*)(ws + ((size_t)4 << 20)); // 4 MB
  unsigned short* Qh = (unsigned short*)(ws + ((size_t)8 << 20));   // 2 MB bf16
  unsigned short* Kh = (unsigned short*)(ws + ((size_t)10 << 20));  // 2 MB
  unsigned* wsk = (unsigned*)(ws + ((size_t)12 << 20));             // 4 MB keys

  qk_proj<<<dim3(NROW / 64), 512, 0, stream>>>(x, Wq, Wk, Qt, Kt, Qh, Kh);
  s_cand<<<2048, 256, 0, stream>>>(Qh, Kh, wsk);
  finalize<<<NROW / 4, 256, 0, stream>>>(Qt, Kt, wsk, out);
}

// Round 4
// 448.313 us; speedup vs baseline: 1.1376x; 1.0465x over previous
//
#include <hip/hip_runtime.h>
#include <math.h>

#define NROW 16384   // B*N rows
#define NCOL 4096
#define CDIM 256
#define DKDIM 64
#define SCALE 0.125f // DK^-0.5

typedef float v4f __attribute__((ext_vector_type(4)));
typedef __attribute__((ext_vector_type(8))) short short8v;  // 8 bf16 = 4 VGPR
typedef __attribute__((ext_vector_type(4))) float f32x4;

// ---- monotone float<->u32 key helpers (unsigned compare == float compare) ----
__device__ __forceinline__ unsigned mono(float v) {
  unsigned u = __float_as_uint(v);
  unsigned s = (unsigned)(((int)u) >> 31);
  return u ^ (s | 0x80000000u);
}
__device__ __forceinline__ float unmono(unsigned k) {
  unsigned u = (k & 0x80000000u) ? (k ^ 0x80000000u) : ~k;
  return __uint_as_float(u);
}
__device__ __forceinline__ unsigned short f2bf(float f) {  // RNE bf16
  unsigned u = __float_as_uint(f);
  u += 0x7FFFu + ((u >> 16) & 1u);
  return (unsigned short)(u >> 16);
}
__device__ __forceinline__ unsigned umaxu(unsigned a, unsigned b) { return a > b ? a : b; }

// ---- top-8 maintenance on packed keys (proven group-of-8 insert logic) ----
__device__ __forceinline__ void ins8(unsigned tk[8], unsigned& tmin, int& tmpos, unsigned v) {
  #pragma unroll
  for (int j = 0; j < 8; ++j) if (j == tmpos) tk[j] = v;
  tmin = tk[0]; tmpos = 0;
  #pragma unroll
  for (int j = 1; j < 8; ++j) if (tk[j] < tmin) { tmin = tk[j]; tmpos = j; }
}
__device__ __forceinline__ unsigned umax8(const unsigned kv[8]) {
  unsigned a = umaxu(umaxu(kv[0], kv[1]), umaxu(kv[2], kv[3]));
  unsigned b = umaxu(umaxu(kv[4], kv[5]), umaxu(kv[6], kv[7]));
  return umaxu(a, b);
}
__device__ __forceinline__ void seed8r(const unsigned kv[8],
                                       unsigned tk[8], unsigned& tmin, int& tmpos) {
  #pragma unroll
  for (int j = 0; j < 8; ++j) tk[j] = kv[j];
  tmin = tk[0]; tmpos = 0;
  #pragma unroll
  for (int j = 1; j < 8; ++j) if (tk[j] < tmin) { tmin = tk[j]; tmpos = j; }
}
__device__ __forceinline__ void scan8r(const unsigned kvin[8],
                                       unsigned tk[8], unsigned& tmin, int& tmpos) {
  unsigned kv[8];
  #pragma unroll
  for (int j = 0; j < 8; ++j) kv[j] = kvin[j];
  unsigned gm = umax8(kv);
  #pragma unroll
  for (int pass = 0; pass < 2; ++pass) {
    if (__any(gm > tmin)) {            // wave-uniform branch
      if (gm > tmin) {                 // per-lane insert (keys unique: col in low bits)
        ins8(tk, tmin, tmpos, gm);
        #pragma unroll
        for (int j = 0; j < 8; ++j) if (kv[j] == gm) kv[j] = 0u;
      }
      gm = umax8(kv);
    }
  }
  if (__any(gm > tmin)) {              // rare: >=3 qualifiers in this group
    #pragma unroll
    for (int j = 0; j < 8; ++j) if (kv[j] > tmin) ins8(tk, tmin, tmpos, kv[j]);
  }
}
__device__ __forceinline__ void seed8(const unsigned* __restrict__ sp,
                                      unsigned tk[8], unsigned& tmin, int& tmpos) {
  uint4 ka = *(const uint4*)(sp);
  uint4 kb = *(const uint4*)(sp + 4);
  unsigned kv[8] = {ka.x, ka.y, ka.z, ka.w, kb.x, kb.y, kb.z, kb.w};
  seed8r(kv, tk, tmin, tmpos);
}
__device__ __forceinline__ void scan8(const unsigned* __restrict__ sp,
                                      unsigned tk[8], unsigned& tmin, int& tmpos) {
  uint4 ka = *(const uint4*)(sp);
  uint4 kb = *(const uint4*)(sp + 4);
  unsigned kv[8] = {ka.x, ka.y, ka.z, ka.w, kb.x, kb.y, kb.z, kb.w};
  scan8r(kv, tk, tmin, tmpos);
}

// ---------------- Kernel 1: fused Q/K projection (fp32 + bf16 row-major) ----
__global__ __launch_bounds__(512, 2) void qk_proj(
    const float* __restrict__ x, const float* __restrict__ Wq,
    const float* __restrict__ Wk, float* __restrict__ Qt,
    float* __restrict__ Kt, unsigned short* __restrict__ Qh,
    unsigned short* __restrict__ Kh) {
  __shared__ float4 xs4[64][65];  // row stride 65 f4-units -> bank-group spread
  const int t = threadIdx.x;
  const int rb = blockIdx.x;      // 256 blocks of 64 rows
  {
    const float4* xg = (const float4*)(x + (size_t)rb * 64 * CDIM);
    #pragma unroll
    for (int i = 0; i < 8; ++i) {
      int idx = i * 512 + t;      // 0..4095
      xs4[idx >> 6][idx & 63] = xg[idx];
    }
  }
  __syncthreads();

  const int lane = t & 63;
  const int wu = __builtin_amdgcn_readfirstlane(t >> 6);  // wave id, uniform
  const int proj = wu >> 2;
  const int chunk = wu & 3;       // d-chunk: d = chunk*16 .. +15
  const float* __restrict__ Wp = proj ? Wk : Wq;

  float acc[16];
  #pragma unroll
  for (int j = 0; j < 16; ++j) acc[j] = 0.f;

  #pragma unroll 4
  for (int cs = 0; cs < 64; ++cs) {        // 4 c's per step
    float4 xv = xs4[lane][cs];
    const float xc[4] = {xv.x, xv.y, xv.z, xv.w};
    #pragma unroll
    for (int i = 0; i < 4; ++i) {
      const float4* __restrict__ w4 =
          (const float4*)(Wp + (size_t)(cs * 4 + i) * DKDIM + chunk * 16);
      float4 wa = w4[0], wb = w4[1], wc = w4[2], wd = w4[3];
      float xi = xc[i];
      acc[0]  = fmaf(xi, wa.x, acc[0]);  acc[1]  = fmaf(xi, wa.y, acc[1]);
      acc[2]  = fmaf(xi, wa.z, acc[2]);  acc[3]  = fmaf(xi, wa.w, acc[3]);
      acc[4]  = fmaf(xi, wb.x, acc[4]);  acc[5]  = fmaf(xi, wb.y, acc[5]);
      acc[6]  = fmaf(xi, wb.z, acc[6]);  acc[7]  = fmaf(xi, wb.w, acc[7]);
      acc[8]  = fmaf(xi, wc.x, acc[8]);  acc[9]  = fmaf(xi, wc.y, acc[9]);
      acc[10] = fmaf(xi, wc.z, acc[10]); acc[11] = fmaf(xi, wc.w, acc[11]);
      acc[12] = fmaf(xi, wd.x, acc[12]); acc[13] = fmaf(xi, wd.y, acc[13]);
      acc[14] = fmaf(xi, wd.z, acc[14]); acc[15] = fmaf(xi, wd.w, acc[15]);
    }
  }

  const int gr = rb * 64 + lane;  // global row
  float* Of = (proj ? Kt : Qt) + (size_t)gr * 64 + chunk * 16;
  #pragma unroll
  for (int i = 0; i < 4; ++i) {
    float4 o = {acc[4 * i], acc[4 * i + 1], acc[4 * i + 2], acc[4 * i + 3]};
    ((float4*)Of)[i] = o;
  }
  unsigned short* Oh = (proj ? Kh : Qh) + (size_t)gr * 64 + chunk * 16;
  unsigned hp[8];
  #pragma unroll
  for (int i = 0; i < 8; ++i)
    hp[i] = (unsigned)f2bf(acc[2 * i]) | ((unsigned)f2bf(acc[2 * i + 1]) << 16);
  uint4 h0 = {hp[0], hp[1], hp[2], hp[3]};
  uint4 h1 = {hp[4], hp[5], hp[6], hp[7]};
  ((uint4*)Oh)[0] = h0;
  ((uint4*)Oh)[1] = h1;
}

// ---------------- Kernel 2: FUSED S + top-k + exact recompute + softmax -----
// Block = 32 rows x 4096 cols, 4 waves. Wave (rg,h): rows rg*16..+15, cols
// h*2048..+2047. Phase 1: MFMA tiles + register scan8r -> per-stream top-8 ->
// LDS (256 keys/row). Phase 2: 8 lanes/row scan 32 keys -> 64 candidates/row
// (coverage provably superset of the row's bf16-top-8: each candidate competes
// only within its 32-key subset). Phase 3: exact fp32 recompute of 64
// candidates (same fma order as before), shuffle top-8 extraction, softmax ->
// LDS. Phase 4: pure NT-store pass writing each 16 KB row with the 8 values
// patched via compare-select. No global load ever follows a global store
// within a wave -> no vmcnt entanglement.
__global__ __launch_bounds__(256, 2) void s_fused(
    const unsigned short* __restrict__ Qh, const unsigned short* __restrict__ Kh,
    const float* __restrict__ Qt, const float* __restrict__ Kt,
    float* __restrict__ out) {
  __shared__ unsigned keys[32 * 260];   // 33280 B (pad 260: bank spread)
  __shared__ unsigned cand[32][64];     // 8192 B
  __shared__ float    pval[32][8];      // 1 KB
  __shared__ int      pcol[32][8];      // 1 KB

  const int t = threadIdx.x;
  const int lane = t & 63;
  const int wu = __builtin_amdgcn_readfirstlane(t >> 6);
  const int rg = wu >> 1;          // row-group: 0 -> rows 0-15, 1 -> 16-31
  const int h = wu & 1;            // col half: h*2048
  // XCD-chunked bijective swizzle (512 = 8*64)
  const int bid = blockIdx.x;
  const int orig = (bid & 7) * 64 + (bid >> 3);
  const int blockrow = orig * 32;  // global row base
  const int b = blockrow >> 12;    // batch

  const int l15 = lane & 15, lk = lane >> 4;
  // A-fragments: my 16 Q rows. row = lane&15, k = (lane>>4)*8+j (+32 for a1).
  const int rowg = blockrow + rg * 16 + l15;
  const short8v a0 = *(const short8v*)(Qh + (size_t)rowg * 64 + lk * 8);
  const short8v a1 = *(const short8v*)(Qh + (size_t)rowg * 64 + lk * 8 + 32);

  const unsigned short* Kb = Kh + ((size_t)(b << 12)) * 64;

  // ---- Phase 1: MFMA + register scan over my 2048 cols ----
  unsigned tk[4][8]; unsigned tmin[4]; int tmpos[4];
  #pragma unroll 1
  for (int g = 0; g < 16; ++g) {   // 16 groups of 8 col-tiles
    unsigned kv[4][8];
    #pragma unroll
    for (int t8 = 0; t8 < 8; ++t8) {
      const int col = h * 2048 + (g * 8 + t8) * 16 + l15;
      const unsigned short* kp = Kb + (size_t)col * 64 + lk * 8;
      const short8v b0 = *(const short8v*)(kp);        // B: col=lane&15, k-half 0
      const short8v b1 = *(const short8v*)(kp + 32);   // k-half 1
      f32x4 acc = {0.f, 0.f, 0.f, 0.f};
      acc = __builtin_amdgcn_mfma_f32_16x16x32_bf16(a0, b0, acc, 0, 0, 0);
      acc = __builtin_amdgcn_mfma_f32_16x16x32_bf16(a1, b1, acc, 0, 0, 0);
      // C/D: col=lane&15, row=(lane>>4)*4+i (m89-verified). Pack to keys.
      #pragma unroll
      for (int i = 0; i < 4; ++i)
        kv[i][t8] = (mono(acc[i]) & 0xFFFFF000u) | (unsigned)col;
    }
    if (g == 0) {
      #pragma unroll
      for (int i = 0; i < 4; ++i) seed8r(kv[i], tk[i], tmin[i], tmpos[i]);
    } else {
      #pragma unroll
      for (int i = 0; i < 4; ++i) scan8r(kv[i], tk[i], tmin[i], tmpos[i]);
    }
  }
  // write per-stream top-8: keys[row][h*128 + l15*8 .. +7], row = rg*16+lk*4+i
  #pragma unroll
  for (int i = 0; i < 4; ++i) {
    unsigned* kr = keys + (rg * 16 + lk * 4 + i) * 260 + h * 128 + l15 * 8;
    uint4 s0 = {tk[i][0], tk[i][1], tk[i][2], tk[i][3]};
    uint4 s1 = {tk[i][4], tk[i][5], tk[i][6], tk[i][7]};
    ((uint4*)kr)[0] = s0; ((uint4*)kr)[1] = s1;
  }
  __syncthreads();

  // ---- Phase 2: 8 lanes/row, each scans 32 keys -> 8 -> 64 candidates/row --
  {
    const int row = t >> 3, q = t & 7;
    const unsigned* sp = keys + row * 260 + q * 32;
    unsigned mt[8]; unsigned mmin; int mmpos;
    seed8(sp, mt, mmin, mmpos);
    scan8(sp + 8, mt, mmin, mmpos);
    scan8(sp + 16, mt, mmin, mmpos);
    scan8(sp + 24, mt, mmin, mmpos);
    uint4 o0 = {mt[0], mt[1], mt[2], mt[3]};
    uint4 o1 = {mt[4], mt[5], mt[6], mt[7]};
    uint4* cp = (uint4*)(&cand[row][q * 8]);
    cp[0] = o0; cp[1] = o1;
  }
  __syncthreads();

  // ---- Phase 3: exact fp32 recompute of 64 candidates, top-8, softmax -----
  #pragma unroll 1
  for (int p = 0; p < 8; ++p) {
    const int rr = p * 4 + wu;     // my wave's row this pass
    const unsigned key = cand[rr][lane];
    const int col = (int)(key & 0xFFFu);
    const float4* Kp = (const float4*)(Kt + ((size_t)((b << 12) + col)) * 64);
    const float4* Qp = (const float4*)(Qt + (size_t)(blockrow + rr) * 64);  // uniform
    float s = 0.f;
    #pragma unroll
    for (int g2 = 0; g2 < 16; ++g2) {
      float4 qf = Qp[g2];
      float4 kf = Kp[g2];
      s = fmaf(qf.x, kf.x, s);
      s = fmaf(qf.y, kf.y, s);
      s = fmaf(qf.z, kf.z, s);
      s = fmaf(qf.w, kf.w, s);
    }
    unsigned kx = mono(s);  // full precision: exact ordering
    float vals[8]; int cols[8];
    #pragma unroll
    for (int it = 0; it < 8; ++it) {
      unsigned m = kx;
      #pragma unroll
      for (int d = 1; d < 64; d <<= 1) m = umaxu(m, (unsigned)__shfl_xor((int)m, d, 64));
      unsigned long long win = __ballot(kx == m);
      int wl = (int)__ffsll(win) - 1;
      cols[it] = __shfl(col, wl, 64);
      vals[it] = unmono(m);
      if (lane == wl) kx = 0u;   // exclude winner
    }
    float vq[8]; float sum = 0.f;
    #pragma unroll
    for (int it = 0; it < 8; ++it) { vq[it] = __expf((vals[it] - vals[0]) * SCALE); sum += vq[it]; }
    float inv = 1.f / sum;
    if (lane < 8) {
      pval[rr][lane] = vq[lane] * inv;
      pcol[rr][lane] = cols[lane];
    }
  }
  __syncthreads();

  // ---- Phase 4: pure NT-store pass (zero-fill + patch), 8 rows per wave ----
  #pragma unroll 1
  for (int j = 0; j < 8; ++j) {
    const int sr = wu * 8 + j;     // block-local row
    float vq[8]; int cols[8];
    #pragma unroll
    for (int q2 = 0; q2 < 8; ++q2) { vq[q2] = pval[sr][q2]; cols[q2] = pcol[sr][q2]; }
    v4f* orow4 = (v4f*)(out + ((size_t)(blockrow + sr) << 12));
    #pragma unroll
    for (int i = 0; i < 16; ++i) {
      const int base = i * 256 + lane * 4;
      v4f z = {0.f, 0.f, 0.f, 0.f};
      #pragma unroll
      for (int q2 = 0; q2 < 8; ++q2) {
        z.x = (cols[q2] == base)     ? vq[q2] : z.x;
        z.y = (cols[q2] == base + 1) ? vq[q2] : z.y;
        z.z = (cols[q2] == base + 2) ? vq[q2] : z.z;
        z.w = (cols[q2] == base + 3) ? vq[q2] : z.w;
      }
      __builtin_nontemporal_store(z, &orow4[(size_t)i * 64 + lane]);
    }
  }
}

extern "C" void kernel_launch(void* const* d_in, const int* in_sizes, int n_in,
                              void* d_out, int out_size, void* d_ws, size_t ws_size,
                              hipStream_t stream) {
  const float* x  = (const float*)d_in[0];
  const float* Wq = (const float*)d_in[1];
  const float* Wk = (const float*)d_in[2];
  float* out = (float*)d_out;

  char* ws = (char*)d_ws;                       // 12 MB used
  float* Qt = (float*)ws;                       // 4 MB fp32 [row][64]
  float* Kt = (float*)(ws + ((size_t)4 << 20)); // 4 MB
  unsigned short* Qh = (unsigned short*)(ws + ((size_t)8 << 20));   // 2 MB bf16
  unsigned short* Kh = (unsigned short*)(ws + ((size_t)10 << 20));  // 2 MB

  qk_proj<<<dim3(NROW / 64), 512, 0, stream>>>(x, Wq, Wk, Qt, Kt, Qh, Kh);
  s_fused<<<512, 256, 0, stream>>>(Qh, Kh, Qt, Kt, out);
}